// Round 5
// baseline (80.089 us; speedup 1.0000x reference)
//
#include <hip/hip_runtime.h>
#include <hip/hip_fp16.h>

// ROI pooling: crop_and_resize (bilinear, 14x14) + 2x2 max pool -> (256,7,7,512) fp32
// feature_maps: (2,50,50,512) fp32 NHWC ; rois: (2,128,4) fp32
// reference permutes [1,0,3,2] -> y1=roi[1], x1=roi[0], y2=roi[3], x2=roi[2]
//
// R9: persistent waves + 2-deep cross-task software pipeline.
// R6 (cache policy), R7 (2px/wave), R8 (VGPR cap lift + single-exposure loads)
// were ALL neutral -> the per-task latency chain (setup -> 16 L3-served taps ->
// consume -> die) is structural: one-shot waves can never overlap task i's
// latency with task i+1's work, and ~12 serialized block-rounds/CU pay it
// every time. Fix: 512 persistent blocks (exactly 2/CU), each wave owns 7
// tasks (grid-stride 2048). Double-buffered NAMED tap registers (A/B, hand
// unrolled -> no runtime indexing/scratch): while consuming task i, task
// i+1's 16 tap loads + rois s_load + decode are already in flight.
// ~175 VGPR, fits launch_bounds(256,2). Tail: clamp task, guard store.
// fp16 taps, scalar (readfirstlane) addresses, NT output stores kept from R8.

constexpr int H = 50, W = 50, C = 512;
constexpr int POOLEDX = 7, KSIZE = 2, CROP = 14;
constexpr int RPB = 128;
constexpr int PIX = POOLEDX * POOLEDX;     // 49
constexpr int NROI = 2 * RPB;              // 256
constexpr int NTASK = NROI * PIX;          // 12544 output pixels
constexpr int NELEM = 2 * H * W * C;       // 2,560,000 floats
constexpr int PBLK  = 512;                 // persistent blocks (2 per CU)
constexpr int NWAVE = PBLK * 4;            // 2048 waves
constexpr int NITER = 7;                   // ceil(12544 / 2048)

typedef _Float16 h8 __attribute__((ext_vector_type(8)));
typedef float    f4 __attribute__((ext_vector_type(4)));

// ---------- pre-pass: fm fp32 -> fp16 into workspace ----------
__global__ __launch_bounds__(256) void cvt_kernel(
    const float* __restrict__ in, __half* __restrict__ out)
{
    const int i = (blockIdx.x * 256 + threadIdx.x) * 8;
    const f4* in4 = reinterpret_cast<const f4*>(in + i);
    const f4 a = __builtin_nontemporal_load(in4);      // read-once fp32
    const f4 b = __builtin_nontemporal_load(in4 + 1);
    _Float16 h[8];
    h[0] = (_Float16)a[0]; h[1] = (_Float16)a[1];
    h[2] = (_Float16)a[2]; h[3] = (_Float16)a[3];
    h[4] = (_Float16)b[0]; h[5] = (_Float16)b[1];
    h[6] = (_Float16)b[2]; h[7] = (_Float16)b[3];
    *reinterpret_cast<f4*>(out + i) = *reinterpret_cast<const f4*>(h);
}

// ---- per-buffer state (named registers only; no arrays -> no scratch) ----
#define DECLBUF(S)                                                           \
    h8 S##q0, S##q1, S##q2,  S##q3,  S##q4,  S##q5,  S##q6,  S##q7,          \
       S##q8, S##q9, S##q10, S##q11, S##q12, S##q13, S##q14, S##q15;         \
    float S##wx0, S##wx1, S##wy0, S##wy1, S##m00, S##m01, S##m10, S##m11;    \
    int S##task;

// setup + issue all 16 tap loads for task T into buffer S
#define TFETCH(S, T)                                                         \
  {                                                                          \
    S##task = (T);                                                           \
    const int tc  = min(S##task, NTASK - 1);                                 \
    const int n   = tc / PIX;                                                \
    const int kk  = tc - n * PIX;                                            \
    const int ph  = kk / POOLEDX;                                            \
    const int pw  = kk - ph * POOLEDX;                                       \
    const int boff = (n / RPB) * (H * W * C);                                \
    const float rx1 = rois[n*4+0], ry1 = rois[n*4+1];                        \
    const float rx2 = rois[n*4+2], ry2 = rois[n*4+3];                        \
    const float ybase = ry1 * (float)(H-1);                                  \
    const float xbase = rx1 * (float)(W-1);                                  \
    const float ystep = ((ry2-ry1)*(float)(H-1)) * (1.0f/(float)(CROP-1));   \
    const float xstep = ((rx2-rx1)*(float)(W-1)) * (1.0f/(float)(CROP-1));   \
    const float xs0 = xbase + (float)(pw*KSIZE+0)*xstep;                     \
    const float xs1 = xbase + (float)(pw*KSIZE+1)*xstep;                     \
    const float ys0 = ybase + (float)(ph*KSIZE+0)*ystep;                     \
    const float ys1 = ybase + (float)(ph*KSIZE+1)*ystep;                     \
    const float mx0 = (xs0>=0.0f && xs0<=(float)(W-1)) ? 1.0f : 0.0f;        \
    const float mx1 = (xs1>=0.0f && xs1<=(float)(W-1)) ? 1.0f : 0.0f;        \
    const float my0 = (ys0>=0.0f && ys0<=(float)(H-1)) ? 1.0f : 0.0f;        \
    const float my1 = (ys1>=0.0f && ys1<=(float)(H-1)) ? 1.0f : 0.0f;        \
    const float xf0 = floorf(xs0), xf1 = floorf(xs1);                        \
    const float yf0 = floorf(ys0), yf1 = floorf(ys1);                        \
    S##wx0 = xs0 - xf0; S##wx1 = xs1 - xf1;                                  \
    S##wy0 = ys0 - yf0; S##wy1 = ys1 - yf1;                                  \
    S##m00 = mx0*my0; S##m01 = mx1*my0;                                      \
    S##m10 = mx0*my1; S##m11 = mx1*my1;                                      \
    int xi0 = (int)xf0; xi0 = min(max(xi0,0),W-1);                           \
    int xi1 = (int)xf1; xi1 = min(max(xi1,0),W-1);                           \
    int yi0 = (int)yf0; yi0 = min(max(yi0,0),H-1);                           \
    int yi1 = (int)yf1; yi1 = min(max(yi1,0),H-1);                           \
    const int cx00 = __builtin_amdgcn_readfirstlane(xi0) * C;                \
    const int cx10 = __builtin_amdgcn_readfirstlane(min(xi0+1,W-1)) * C;     \
    const int cx01 = __builtin_amdgcn_readfirstlane(xi1) * C;                \
    const int cx11 = __builtin_amdgcn_readfirstlane(min(xi1+1,W-1)) * C;     \
    const int ry00 = __builtin_amdgcn_readfirstlane(yi0) * (W*C);            \
    const int ry10 = __builtin_amdgcn_readfirstlane(min(yi0+1,H-1)) * (W*C); \
    const int ry01 = __builtin_amdgcn_readfirstlane(yi1) * (W*C);            \
    const int ry11 = __builtin_amdgcn_readfirstlane(min(yi1+1,H-1)) * (W*C); \
    const __half* bb = lanebase + boff;                                      \
    S##q0  = *reinterpret_cast<const h8*>(bb + ry00 + cx00);                 \
    S##q1  = *reinterpret_cast<const h8*>(bb + ry00 + cx10);                 \
    S##q2  = *reinterpret_cast<const h8*>(bb + ry10 + cx00);                 \
    S##q3  = *reinterpret_cast<const h8*>(bb + ry10 + cx10);                 \
    S##q4  = *reinterpret_cast<const h8*>(bb + ry00 + cx01);                 \
    S##q5  = *reinterpret_cast<const h8*>(bb + ry00 + cx11);                 \
    S##q6  = *reinterpret_cast<const h8*>(bb + ry10 + cx01);                 \
    S##q7  = *reinterpret_cast<const h8*>(bb + ry10 + cx11);                 \
    S##q8  = *reinterpret_cast<const h8*>(bb + ry01 + cx00);                 \
    S##q9  = *reinterpret_cast<const h8*>(bb + ry01 + cx10);                 \
    S##q10 = *reinterpret_cast<const h8*>(bb + ry11 + cx00);                 \
    S##q11 = *reinterpret_cast<const h8*>(bb + ry11 + cx10);                 \
    S##q12 = *reinterpret_cast<const h8*>(bb + ry01 + cx01);                 \
    S##q13 = *reinterpret_cast<const h8*>(bb + ry01 + cx11);                 \
    S##q14 = *reinterpret_cast<const h8*>(bb + ry11 + cx01);                 \
    S##q15 = *reinterpret_cast<const h8*>(bb + ry11 + cx11);                 \
  }

#define TGROUP(S, QA, QB, QC, QD, WY, WX, M)                                 \
  { const float wy = S##WY, wx = S##WX, m = S##M;                            \
    const _Float16 w00 = (_Float16)((1.0f-wy)*(1.0f-wx)*m);                  \
    const _Float16 w01 = (_Float16)((1.0f-wy)*wx*m);                         \
    const _Float16 w10 = (_Float16)(wy*(1.0f-wx)*m);                         \
    const _Float16 w11 = (_Float16)(wy*wx*m);                                \
    const h8 v = S##QA*w00 + S##QB*w01 + S##QC*w10 + S##QD*w11;              \
    acc = __builtin_elementwise_max(acc, v); }

// consume buffer S: bilinear + 2x2 max + guarded NT store
#define TCONSUME(S)                                                          \
  {                                                                          \
    h8 acc;                                                                  \
    _Pragma("unroll")                                                        \
    for (int c = 0; c < 8; ++c) acc[c] = (_Float16)(-60000.0f);              \
    TGROUP(S, q0,  q1,  q2,  q3,  wy0, wx0, m00)                             \
    TGROUP(S, q4,  q5,  q6,  q7,  wy0, wx1, m01)                             \
    TGROUP(S, q8,  q9,  q10, q11, wy1, wx0, m10)                             \
    TGROUP(S, q12, q13, q14, q15, wy1, wx1, m11)                             \
    if (S##task < NTASK) {                                                   \
      f4 o0, o1;                                                             \
      o0[0]=(float)acc[0]; o0[1]=(float)acc[1];                              \
      o0[2]=(float)acc[2]; o0[3]=(float)acc[3];                              \
      o1[0]=(float)acc[4]; o1[1]=(float)acc[5];                              \
      o1[2]=(float)acc[6]; o1[3]=(float)acc[7];                              \
      f4* out4 = reinterpret_cast<f4*>(out) + (long)S##task*(C/4) + lane*2;  \
      __builtin_nontemporal_store(o0, out4);                                 \
      __builtin_nontemporal_store(o1, out4 + 1);                             \
    }                                                                        \
  }

// ---------- main: 512 persistent blocks, 7 tasks/wave, A/B pipelined ----------
__global__ __launch_bounds__(256, 2) void roi_pool_kernel(
    const __half* __restrict__ fmh,
    const float* __restrict__ rois,
    float* __restrict__ out)
{
    const int wv   = __builtin_amdgcn_readfirstlane((int)(threadIdx.x >> 6));
    const int lane = threadIdx.x & 63;                  // channels 8*lane..
    const int wave = blockIdx.x * 4 + wv;               // 0..2047
    const __half* lanebase = fmh + lane * 8;

    DECLBUF(A)
    DECLBUF(B)

    TFETCH(A, wave)                    // i=0
    TFETCH(B, wave + 1*NWAVE)          // i=1 in flight
    TCONSUME(A)                        // i=0
    TFETCH(A, wave + 2*NWAVE)          // i=2 in flight
    TCONSUME(B)                        // i=1
    TFETCH(B, wave + 3*NWAVE)          // i=3
    TCONSUME(A)                        // i=2
    TFETCH(A, wave + 4*NWAVE)          // i=4
    TCONSUME(B)                        // i=3
    TFETCH(B, wave + 5*NWAVE)          // i=5
    TCONSUME(A)                        // i=4
    TFETCH(A, wave + 6*NWAVE)          // i=6
    TCONSUME(B)                        // i=5
    TCONSUME(A)                        // i=6
}

extern "C" void kernel_launch(void* const* d_in, const int* in_sizes, int n_in,
                              void* d_out, int out_size, void* d_ws, size_t ws_size,
                              hipStream_t stream) {
    const float* fm   = (const float*)d_in[0];
    const float* rois = (const float*)d_in[1];
    float* out  = (float*)d_out;
    __half* fmh = (__half*)d_ws;                       // 5.12 MB << ws_size

    cvt_kernel<<<NELEM / (256 * 8), 256, 0, stream>>>(fm, fmh);     // 1250 blocks
    roi_pool_kernel<<<PBLK, 256, 0, stream>>>(fmh, rois, out);      // 512 blocks
}

// Round 6
// 78.706 us; speedup vs baseline: 1.0176x; 1.0176x over previous
//
#include <hip/hip_runtime.h>
#include <hip/hip_fp16.h>

// ROI pooling: crop_and_resize (bilinear, 14x14) + 2x2 max pool -> (256,7,7,512) fp32
// feature_maps: (2,50,50,512) fp32 NHWC ; rois: (2,128,4) fp32
// reference permutes [1,0,3,2] -> y1=roi[1], x1=roi[0], y2=roi[3], x2=roi[2]
//
// R10: batch-split XCD placement. R6/R7/R8/R9 (cache policy, MLP, VGPR cap,
// persistent pipeline) were ALL neutral -> roi_pool is bound by the invariant
// none touched: 200 MB of tap reads vs a 5.12 MB map that does NOT fit a
// 4 MiB XCD-L2, with every XCD touching the whole map (random ROI boxes) ->
// L2 thrash, taps L3-served (~10 TB/s) -> ~15-20 us floor.
// Fix: fmh = 2 batches x 2.56 MB; EACH HALF fits a 4 MiB L2. Remap blocks so
// XCDs 0-3 process only batch-0 tasks and XCDs 4-7 only batch-1 (blocks
// dispatch round-robin by bid&7). Per-XCD working set 2.56 MB -> taps hit L2
// after compulsory fill. NT out-stores (kept) stop output evicting the batch.
// Base = R8b; ONLY the swizzle changed, so the delta is attributable.

constexpr int H = 50, W = 50, C = 512;
constexpr int POOLEDX = 7, KSIZE = 2, CROP = 14;
constexpr int RPB = 128;
constexpr int PIX = POOLEDX * POOLEDX;     // 49
constexpr int NROI = 2 * RPB;              // 256
constexpr int NTASK = NROI * PIX;          // 12544 output pixels
constexpr int NELEM = 2 * H * W * C;       // 2,560,000 floats
constexpr int NBLK  = NTASK / 4;           // 3136 blocks
constexpr int HBLK  = NBLK / 2;            // 1568 blocks per batch
constexpr int CHUNK = NBLK / 8;            // 392

typedef _Float16 h8 __attribute__((ext_vector_type(8)));
typedef float    f4 __attribute__((ext_vector_type(4)));

// ---------- pre-pass: fm fp32 -> fp16 into workspace ----------
__global__ __launch_bounds__(256) void cvt_kernel(
    const float* __restrict__ in, __half* __restrict__ out)
{
    const int i = (blockIdx.x * 256 + threadIdx.x) * 8;
    const f4* in4 = reinterpret_cast<const f4*>(in + i);
    const f4 a = __builtin_nontemporal_load(in4);      // read-once fp32
    const f4 b = __builtin_nontemporal_load(in4 + 1);
    _Float16 h[8];
    h[0] = (_Float16)a[0]; h[1] = (_Float16)a[1];
    h[2] = (_Float16)a[2]; h[3] = (_Float16)a[3];
    h[4] = (_Float16)b[0]; h[5] = (_Float16)b[1];
    h[6] = (_Float16)b[2]; h[7] = (_Float16)b[3];
    *reinterpret_cast<f4*>(out + i) = *reinterpret_cast<const f4*>(h);
}

// ---------- main: 4 waves/block, one output pixel per wave ----------
__global__ __launch_bounds__(256, 2) void roi_pool_kernel(
    const __half* __restrict__ fmh,
    const float* __restrict__ rois,
    float* __restrict__ out)
{
    const int wv   = __builtin_amdgcn_readfirstlane((int)(threadIdx.x >> 6));
    const int lane = threadIdx.x & 63;                  // channels 8*lane..

    // batch-split placement: x = bid&7 is the (heuristic) XCD id.
    // XCDs 0-3 -> batch-0 task blocks [0,1568); XCDs 4-7 -> batch-1 [1568,3136).
    // Bijective: (x,j) -> (x>>2)*1568 + (x&3)*392 + j.
    const int bid  = blockIdx.x;
    const int x    = bid & 7;
    const int j    = bid >> 3;                          // 0..391
    const int tb   = (x >> 2) * HBLK + (x & 3) * CHUNK + j;
    const int task = tb * 4 + wv;                       // 0..12543

    const int n  = task / PIX;
    const int k  = task - n * PIX;
    const int ph = k / POOLEDX;
    const int pw = k - ph * POOLEDX;
    const int bat = n / RPB;

    const float rx1 = rois[n*4+0], ry1 = rois[n*4+1];
    const float rx2 = rois[n*4+2], ry2 = rois[n*4+3];
    const float ybase = ry1 * (float)(H - 1);
    const float xbase = rx1 * (float)(W - 1);
    const float ystep = ((ry2 - ry1) * (float)(H - 1)) / (float)(CROP - 1);
    const float xstep = ((rx2 - rx1) * (float)(W - 1)) / (float)(CROP - 1);

    // ---- tap parameters (all wave-uniform) ----
    int   x0i[KSIZE], x1i[KSIZE], y0i[KSIZE], y1i[KSIZE];
    float wxA[KSIZE], wyA[KSIZE];
    float mxA[KSIZE], myA[KSIZE];           // valid masks as 0/1 floats
    #pragma unroll
    for (int kx = 0; kx < KSIZE; ++kx) {
        const float xs = xbase + (float)(pw * KSIZE + kx) * xstep;
        mxA[kx] = ((xs >= 0.0f) && (xs <= (float)(W - 1))) ? 1.0f : 0.0f;
        const float xf = floorf(xs);
        wxA[kx] = xs - xf;
        int xi = (int)xf; xi = min(max(xi, 0), W - 1);
        x0i[kx] = __builtin_amdgcn_readfirstlane(xi);
        x1i[kx] = __builtin_amdgcn_readfirstlane(min(xi + 1, W - 1));
    }
    #pragma unroll
    for (int ky = 0; ky < KSIZE; ++ky) {
        const float ys = ybase + (float)(ph * KSIZE + ky) * ystep;
        myA[ky] = ((ys >= 0.0f) && (ys <= (float)(H - 1))) ? 1.0f : 0.0f;
        const float yf = floorf(ys);
        wyA[ky] = ys - yf;
        int yi = (int)yf; yi = min(max(yi, 0), H - 1);
        y0i[ky] = __builtin_amdgcn_readfirstlane(yi);
        y1i[ky] = __builtin_amdgcn_readfirstlane(min(yi + 1, H - 1));
    }

    const __half* base = fmh + (long)bat * (H * W) * C + lane * 8;

    // ---- phase 1: issue ALL 16 tap loads (independent; one waitcnt later) ----
    const h8 t00a = *reinterpret_cast<const h8*>(base + (y0i[0] * W + x0i[0]) * C);
    const h8 t01a = *reinterpret_cast<const h8*>(base + (y0i[0] * W + x1i[0]) * C);
    const h8 t10a = *reinterpret_cast<const h8*>(base + (y1i[0] * W + x0i[0]) * C);
    const h8 t11a = *reinterpret_cast<const h8*>(base + (y1i[0] * W + x1i[0]) * C);
    const h8 t00b = *reinterpret_cast<const h8*>(base + (y0i[0] * W + x0i[1]) * C);
    const h8 t01b = *reinterpret_cast<const h8*>(base + (y0i[0] * W + x1i[1]) * C);
    const h8 t10b = *reinterpret_cast<const h8*>(base + (y1i[0] * W + x0i[1]) * C);
    const h8 t11b = *reinterpret_cast<const h8*>(base + (y1i[0] * W + x1i[1]) * C);
    const h8 t00c = *reinterpret_cast<const h8*>(base + (y0i[1] * W + x0i[0]) * C);
    const h8 t01c = *reinterpret_cast<const h8*>(base + (y0i[1] * W + x1i[0]) * C);
    const h8 t10c = *reinterpret_cast<const h8*>(base + (y1i[1] * W + x0i[0]) * C);
    const h8 t11c = *reinterpret_cast<const h8*>(base + (y1i[1] * W + x1i[0]) * C);
    const h8 t00d = *reinterpret_cast<const h8*>(base + (y0i[1] * W + x0i[1]) * C);
    const h8 t01d = *reinterpret_cast<const h8*>(base + (y0i[1] * W + x1i[1]) * C);
    const h8 t10d = *reinterpret_cast<const h8*>(base + (y1i[1] * W + x0i[1]) * C);
    const h8 t11d = *reinterpret_cast<const h8*>(base + (y1i[1] * W + x1i[1]) * C);

    // ---- phase 2: consume ----
    h8 acc;
    #pragma unroll
    for (int c = 0; c < 8; ++c) acc[c] = (_Float16)(-60000.0f);

    {
        const float wy = wyA[0], wxk = wxA[0], m = mxA[0] * myA[0];
        const _Float16 w00 = (_Float16)((1.0f - wy) * (1.0f - wxk) * m);
        const _Float16 w01 = (_Float16)((1.0f - wy) * wxk * m);
        const _Float16 w10 = (_Float16)(wy * (1.0f - wxk) * m);
        const _Float16 w11 = (_Float16)(wy * wxk * m);
        const h8 v = t00a * w00 + t01a * w01 + t10a * w10 + t11a * w11;
        acc = __builtin_elementwise_max(acc, v);
    }
    {
        const float wy = wyA[0], wxk = wxA[1], m = mxA[1] * myA[0];
        const _Float16 w00 = (_Float16)((1.0f - wy) * (1.0f - wxk) * m);
        const _Float16 w01 = (_Float16)((1.0f - wy) * wxk * m);
        const _Float16 w10 = (_Float16)(wy * (1.0f - wxk) * m);
        const _Float16 w11 = (_Float16)(wy * wxk * m);
        const h8 v = t00b * w00 + t01b * w01 + t10b * w10 + t11b * w11;
        acc = __builtin_elementwise_max(acc, v);
    }
    {
        const float wy = wyA[1], wxk = wxA[0], m = mxA[0] * myA[1];
        const _Float16 w00 = (_Float16)((1.0f - wy) * (1.0f - wxk) * m);
        const _Float16 w01 = (_Float16)((1.0f - wy) * wxk * m);
        const _Float16 w10 = (_Float16)(wy * (1.0f - wxk) * m);
        const _Float16 w11 = (_Float16)(wy * wxk * m);
        const h8 v = t00c * w00 + t01c * w01 + t10c * w10 + t11c * w11;
        acc = __builtin_elementwise_max(acc, v);
    }
    {
        const float wy = wyA[1], wxk = wxA[1], m = mxA[1] * myA[1];
        const _Float16 w00 = (_Float16)((1.0f - wy) * (1.0f - wxk) * m);
        const _Float16 w01 = (_Float16)((1.0f - wy) * wxk * m);
        const _Float16 w10 = (_Float16)(wy * (1.0f - wxk) * m);
        const _Float16 w11 = (_Float16)(wy * wxk * m);
        const h8 v = t00d * w00 + t01d * w01 + t10d * w10 + t11d * w11;
        acc = __builtin_elementwise_max(acc, v);
    }

    // epilogue: fp16 -> fp32, two nontemporal float4 stores (write-once)
    f4 o0, o1;
    o0[0] = (float)acc[0]; o0[1] = (float)acc[1]; o0[2] = (float)acc[2]; o0[3] = (float)acc[3];
    o1[0] = (float)acc[4]; o1[1] = (float)acc[5]; o1[2] = (float)acc[6]; o1[3] = (float)acc[7];
    f4* out4 = reinterpret_cast<f4*>(out) + (long)task * (C / 4) + lane * 2;
    __builtin_nontemporal_store(o0, out4);
    __builtin_nontemporal_store(o1, out4 + 1);
}

extern "C" void kernel_launch(void* const* d_in, const int* in_sizes, int n_in,
                              void* d_out, int out_size, void* d_ws, size_t ws_size,
                              hipStream_t stream) {
    const float* fm   = (const float*)d_in[0];
    const float* rois = (const float*)d_in[1];
    float* out  = (float*)d_out;
    __half* fmh = (__half*)d_ws;                       // 5.12 MB << ws_size

    cvt_kernel<<<NELEM / (256 * 8), 256, 0, stream>>>(fm, fmh);     // 1250 blocks
    roi_pool_kernel<<<NBLK, 256, 0, stream>>>(fmh, rois, out);      // 3136 blocks
}